// Round 3
// baseline (3256.943 us; speedup 1.0000x reference)
//
#include <hip/hip_runtime.h>

#define NN 50000
#define EE 800000
#define GG 64
#define FF 128
#define NBES 8
#define RMAXF 5.0f
#define PI_F 3.14159265358979323846f

// spherical harmonic constants
#define S3  1.7320508075688772f
#define S5  2.23606797749979f
#define S15 3.872983346207417f
#define C1c 2.091650066335189f   // sqrt(35/8)
#define C2c 10.246950765959598f  // sqrt(105)
#define C3c 1.62018517460196f    // sqrt(21/8)
#define C4c 1.3228756555322954f  // sqrt(7)/2
#define C5c 5.123475382979799f   // sqrt(105)/2
#define CCB 0.6324555320336759f  // sqrt(2/5)

__device__ __forceinline__ float shc_s(float x, float y, float z, const float* __restrict__ w) {
    float x2 = x * x, y2 = y * y, z2 = z * z;
    return w[0]
        + w[1] * (S3 * x) + w[2] * (S3 * y) + w[3] * (S3 * z)
        + w[4] * (S15 * x * y) + w[5] * (S15 * y * z) + w[6] * (0.5f * S5 * (3.f * z2 - 1.f))
        + w[7] * (S15 * x * z) + w[8] * (0.5f * S15 * (x2 - y2))
        + w[9] * (C1c * y * (3.f * x2 - y2)) + w[10] * (C2c * x * y * z)
        + w[11] * (C3c * y * (5.f * z2 - 1.f)) + w[12] * (C4c * z * (5.f * z2 - 3.f))
        + w[13] * (C3c * x * (5.f * z2 - 1.f)) + w[14] * (C5c * z * (x2 - y2))
        + w[15] * (C1c * x * (x2 - 3.f * y2));
}

__device__ __forceinline__ void shc_grad(float x, float y, float z, const float* __restrict__ w,
                                         float& gx, float& gy, float& gz) {
    float x2 = x * x, y2 = y * y, z2 = z * z;
    gx = w[1] * S3 + w[4] * (S15 * y) + w[7] * (S15 * z) + w[8] * (S15 * x)
       + w[9] * (6.f * C1c * x * y) + w[10] * (C2c * y * z) + w[13] * (C3c * (5.f * z2 - 1.f))
       + w[14] * (2.f * C5c * x * z) + w[15] * (3.f * C1c * (x2 - y2));
    gy = w[2] * S3 + w[4] * (S15 * x) + w[5] * (S15 * z) - w[8] * (S15 * y)
       + w[9] * (3.f * C1c * (x2 - y2)) + w[10] * (C2c * x * z) + w[11] * (C3c * (5.f * z2 - 1.f))
       - w[14] * (2.f * C5c * y * z) - w[15] * (6.f * C1c * x * y);
    gz = w[3] * S3 + w[5] * (S15 * y) + w[6] * (3.f * S5 * z) + w[7] * (S15 * x)
       + w[10] * (C2c * x * y) + w[11] * (10.f * C3c * y * z) + w[12] * (C4c * (15.f * z2 - 3.f))
       + w[13] * (10.f * C3c * x * z) + w[14] * (C5c * (x2 - y2));
}

// geo SoA layout (arrays of EE floats)
#define G_EB(k)  ((size_t)(k) * EE)
#define G_S0     ((size_t)8 * EE)
#define G_S1     ((size_t)9 * EE)
#define G_DB(k)  ((size_t)(10 + (k)) * EE)
#define G_DSP0   ((size_t)18 * EE)
#define G_DRP0   ((size_t)19 * EE)
#define G_DSP1   ((size_t)20 * EE)
#define G_DRP1   ((size_t)21 * EE)

// -------------------- geometry (thread-per-edge) --------------------

__global__ __launch_bounds__(256) void edge_geom(const float* __restrict__ pos,
                                                 const float* __restrict__ shifts,
                                                 const int* __restrict__ ei,
                                                 const float* __restrict__ wsh,  // (2,16)
                                                 float* __restrict__ geo) {
    int e = blockIdx.x * 256 + threadIdx.x;
    if (e >= EE) return;
    int snd = ei[e];
    int rcv = ei[EE + e];
    float vx = pos[rcv * 3 + 0] - pos[snd * 3 + 0] + shifts[e * 3 + 0];
    float vy = pos[rcv * 3 + 1] - pos[snd * 3 + 1] + shifts[e * 3 + 1];
    float vz = pos[rcv * 3 + 2] - pos[snd * 3 + 2] + shifts[e * 3 + 2];
    float r2 = vx * vx + vy * vy + vz * vz + 1e-12f;
    float r = sqrtf(r2);
    float inv_r = 1.0f / r;
    float x = vx * inv_r, y = vy * inv_r, z = vz * inv_r;
    float valid = (r < RMAXF) ? 1.f : 0.f;

    geo[G_S0 + e] = shc_s(x, y, z, wsh);
    geo[G_S1 + e] = shc_s(x, y, z, wsh + 16);

    float u = r * (1.0f / RMAXF);
    float th = PI_F * u;
    float s1 = sinf(th), c1 = cosf(th);
    float u2 = u * u, u3 = u2 * u, u5 = u2 * u3, u6 = u3 * u3, u7 = u6 * u, u8 = u6 * u2;
    float env = (1.f - 28.f * u6 + 48.f * u7 - 21.f * u8) * valid;
    float denv = (-168.f * u5 + 336.f * u6 - 168.f * u7) * (1.0f / RMAXF) * valid;
    float sk = s1, skm = 0.f, ck = c1, ckm = 1.f;
    float tc = 2.f * c1;
#pragma unroll
    for (int k = 1; k <= NBES; k++) {
        float b = CCB * sk * inv_r;
        geo[G_EB(k - 1) + e] = b * env;
        geo[G_DB(k - 1) + e] = CCB * (((float)k * PI_F * (1.0f / RMAXF)) * ck * inv_r
                                      - sk * inv_r * inv_r) * env
                               + b * denv;
        float sn = tc * sk - skm; skm = sk; sk = sn;
        float cn = tc * ck - ckm; ckm = ck; ck = cn;
    }
}

// -------------------- node prep --------------------

// h0 = attrs @ W_emb, 2 nodes per block
__global__ __launch_bounds__(256) void h0_kernel(const float* __restrict__ attrs,
                                                 const float* __restrict__ W_emb,
                                                 float* __restrict__ h0) {
    int sub = threadIdx.x >> 7;
    int f = threadIdx.x & 127;
    int n = blockIdx.x * 2 + sub;
    float acc = 0.f;
#pragma unroll
    for (int a = 0; a < 10; a++) acc += attrs[n * 10 + a] * W_emb[a * FF + f];
    h0[n * FF + f] = acc;
}

// -------------------- edge feature kernels (wave-per-edge, grid-stride) --------------------

__global__ __launch_bounds__(256) void edge_fwd_feat(const float* __restrict__ geo,
                                                     const float* __restrict__ geo_s,
                                                     const int* __restrict__ ei,
                                                     const float* __restrict__ h_src,
                                                     const float* __restrict__ Wr,
                                                     float* __restrict__ agg) {
    int wave = (blockIdx.x * 256 + threadIdx.x) >> 6;
    int lane = threadIdx.x & 63;
    int nwaves = gridDim.x * 4;
    int f0 = lane, f1 = lane + 64;
    float wr0[NBES], wr1[NBES];
#pragma unroll
    for (int k = 0; k < NBES; k++) { wr0[k] = Wr[k * FF + f0]; wr1[k] = Wr[k * FF + f1]; }

    for (int e = wave; e < EE; e += nwaves) {
        int snd = ei[e];
        int rcv = ei[EE + e];
        float s = geo_s[e];
        float R0 = 0.f, R1 = 0.f;
#pragma unroll
        for (int k = 0; k < NBES; k++) {
            float eb = geo[G_EB(k) + e];
            R0 += eb * wr0[k];
            R1 += eb * wr1[k];
        }
        float h0 = h_src[snd * FF + f0];
        float h1 = h_src[snd * FF + f1];
        atomicAdd(&agg[rcv * FF + f0], h0 * R0 * s);
        atomicAdd(&agg[rcv * FF + f1], h1 * R1 * s);
    }
}

template <bool LAYER1>
__global__ __launch_bounds__(256) void edge_bwd_feat(const float* __restrict__ geo,
                                                     const float* __restrict__ geo_s,
                                                     const int* __restrict__ ei,
                                                     const float* __restrict__ h_src,
                                                     const float* __restrict__ Wr,
                                                     const float* __restrict__ a1,
                                                     const float* __restrict__ b0,
                                                     float* __restrict__ gh,
                                                     float* __restrict__ dsp_out,
                                                     float* __restrict__ drp_out) {
    int wave = (blockIdx.x * 256 + threadIdx.x) >> 6;
    int lane = threadIdx.x & 63;
    int nwaves = gridDim.x * 4;
    int f0 = lane, f1 = lane + 64;
    float wr0[NBES], wr1[NBES];
#pragma unroll
    for (int k = 0; k < NBES; k++) { wr0[k] = Wr[k * FF + f0]; wr1[k] = Wr[k * FF + f1]; }
    float dm0u = 0.f, dm1u = 0.f;
    if (LAYER1) { dm0u = a1[f0]; dm1u = a1[f1]; }

    for (int e = wave; e < EE; e += nwaves) {
        int snd = ei[e];
        int rcv = ei[EE + e];
        float R0 = 0.f, R1 = 0.f, Rd0 = 0.f, Rd1 = 0.f;
#pragma unroll
        for (int k = 0; k < NBES; k++) {
            float eb = geo[G_EB(k) + e];
            float db = geo[G_DB(k) + e];
            R0 += eb * wr0[k];
            R1 += eb * wr1[k];
            Rd0 += db * wr0[k];
            Rd1 += db * wr1[k];
        }
        float dm0, dm1;
        if (LAYER1) { dm0 = dm0u; dm1 = dm1u; }
        else        { dm0 = b0[rcv * FF + f0]; dm1 = b0[rcv * FF + f1]; }
        float dh0 = dm0 * h_src[snd * FF + f0];
        float dh1 = dm1 * h_src[snd * FF + f1];
        float dsp = dh0 * R0 + dh1 * R1;
        float drp = dh0 * Rd0 + dh1 * Rd1;
#pragma unroll
        for (int o = 32; o > 0; o >>= 1) {
            dsp += __shfl_xor(dsp, o);
            drp += __shfl_xor(drp, o);
        }
        if (LAYER1) {
            float s = geo_s[e];
            atomicAdd(&gh[snd * FF + f0], dm0 * R0 * s);
            atomicAdd(&gh[snd * FF + f1], dm1 * R1 * s);
        }
        if (lane == 0) { dsp_out[e] = dsp; drp_out[e] = drp; }
    }
}

// -------------------- force finalize (thread-per-edge, both layers) --------------------

__global__ __launch_bounds__(256) void force_kernel(const float* __restrict__ pos,
                                                    const float* __restrict__ shifts,
                                                    const int* __restrict__ ei,
                                                    const float* __restrict__ wsh,
                                                    const float* __restrict__ geo,
                                                    float* __restrict__ forces) {
    int e = blockIdx.x * 256 + threadIdx.x;
    if (e >= EE) return;
    int snd = ei[e];
    int rcv = ei[EE + e];
    float vx = pos[rcv * 3 + 0] - pos[snd * 3 + 0] + shifts[e * 3 + 0];
    float vy = pos[rcv * 3 + 1] - pos[snd * 3 + 1] + shifts[e * 3 + 1];
    float vz = pos[rcv * 3 + 2] - pos[snd * 3 + 2] + shifts[e * 3 + 2];
    float r2 = vx * vx + vy * vy + vz * vz + 1e-12f;
    float r = sqrtf(r2);
    float inv_r = 1.0f / r;
    float x = vx * inv_r, y = vy * inv_r, z = vz * inv_r;

    float dsp0 = geo[G_DSP0 + e], drp0 = geo[G_DRP0 + e];
    float dsp1 = geo[G_DSP1 + e], drp1 = geo[G_DRP1 + e];
    float s0 = geo[G_S0 + e], s1v = geo[G_S1 + e];

    float g0x, g0y, g0z, g1x, g1y, g1z;
    shc_grad(x, y, z, wsh, g0x, g0y, g0z);
    shc_grad(x, y, z, wsh + 16, g1x, g1y, g1z);
    float gux = dsp0 * g0x + dsp1 * g1x;
    float guy = dsp0 * g0y + dsp1 * g1y;
    float guz = dsp0 * g0z + dsp1 * g1z;
    float gr = s0 * drp0 + s1v * drp1;
    float dgu = gux * x + guy * y + guz * z;
    float gvx = gr * x + inv_r * (gux - dgu * x);
    float gvy = gr * y + inv_r * (guy - dgu * y);
    float gvz = gr * z + inv_r * (guz - dgu * z);
    atomicAdd(&forces[snd * 3 + 0], gvx);
    atomicAdd(&forces[snd * 3 + 1], gvy);
    atomicAdd(&forces[snd * 3 + 2], gvz);
    atomicAdd(&forces[rcv * 3 + 0], -gvx);
    atomicAdd(&forces[rcv * 3 + 1], -gvy);
    atomicAdd(&forces[rcv * 3 + 2], -gvz);
}

// -------------------- tiled node GEMM: C[n][f] = sum_k A[n][k] B[k][f] (+ epi) ----------
// 32 nodes/block, 256 threads (4 waves). wave w owns nodes n0+8w..+7;
// lane L owns f0=L, f1=L+64. A-tile staged in LDS.
template <bool WITH_EPI>
__global__ __launch_bounds__(256) void node_gemm(const float* __restrict__ A,
                                                 const float* __restrict__ B,
                                                 const float* __restrict__ attrs,
                                                 const float* __restrict__ Wskip,
                                                 const float* __restrict__ wread,
                                                 const int* __restrict__ batch,
                                                 float* __restrict__ C,
                                                 float* __restrict__ energy) {
    __shared__ float sa[32][FF];
    int tid = threadIdx.x;
    int w = tid >> 6;
    int lane = tid & 63;
    int n0 = blockIdx.x * 32;

    // stage A tile (32x128 f32) via coalesced float4 loads
#pragma unroll
    for (int j = 0; j < 4; j++) {
        int flat = (j * 256 + tid) * 4;           // 0..4095 step 4
        int row = flat >> 7;
        int col = flat & 127;
        int n = n0 + row;
        float4 v;
        if (n < NN) v = *(const float4*)&A[(size_t)n * FF + col];
        else        v = make_float4(0.f, 0.f, 0.f, 0.f);
        *(float4*)&sa[row][col] = v;
    }
    __syncthreads();

    int f0 = lane, f1 = lane + 64;
    float acc[8][2];
#pragma unroll
    for (int i = 0; i < 8; i++) { acc[i][0] = 0.f; acc[i][1] = 0.f; }

    for (int kk = 0; kk < FF; kk += 4) {
        float4 av[8];
#pragma unroll
        for (int i = 0; i < 8; i++) av[i] = *(const float4*)&sa[w * 8 + i][kk];
#pragma unroll
        for (int q = 0; q < 4; q++) {
            float b0 = B[(kk + q) * FF + f0];
            float b1 = B[(kk + q) * FF + f1];
#pragma unroll
            for (int i = 0; i < 8; i++) {
                float a = (q == 0) ? av[i].x : (q == 1) ? av[i].y : (q == 2) ? av[i].z : av[i].w;
                acc[i][0] += a * b0;
                acc[i][1] += a * b1;
            }
        }
    }

#pragma unroll
    for (int i = 0; i < 8; i++) {
        int n = n0 + w * 8 + i;
        if (n >= NN) continue;
        if (WITH_EPI) {
#pragma unroll
            for (int a = 0; a < 10; a++) {
                float att = attrs[n * 10 + a];
                acc[i][0] += att * Wskip[a * FF + f0];
                acc[i][1] += att * Wskip[a * FF + f1];
            }
        }
        C[(size_t)n * FF + f0] = acc[i][0];
        C[(size_t)n * FF + f1] = acc[i][1];
        if (WITH_EPI) {
            float p = acc[i][0] * wread[f0] + acc[i][1] * wread[f1];
#pragma unroll
            for (int o = 32; o > 0; o >>= 1) p += __shfl_xor(p, o);
            if (lane == 0) atomicAdd(&energy[batch[n]], p);
        }
    }
}

// -------------------- layer-1 energy (dot) + e0, 4 nodes/block (1/wave) ----------------
__global__ __launch_bounds__(256) void e1_dot(const float* __restrict__ agg,
                                              const float* __restrict__ attrs,
                                              const float* __restrict__ a1,
                                              const float* __restrict__ askip,  // askip1+ae (10)
                                              const int* __restrict__ batch,
                                              float* __restrict__ energy) {
    int w = threadIdx.x >> 6;
    int lane = threadIdx.x & 63;
    int n = blockIdx.x * 4 + w;
    if (n >= NN) return;
    float p = agg[(size_t)n * FF + lane] * a1[lane]
            + agg[(size_t)n * FF + lane + 64] * a1[lane + 64];
    if (lane < 10) p += attrs[n * 10 + lane] * askip[lane];
#pragma unroll
    for (int o = 32; o > 0; o >>= 1) p += __shfl_xor(p, o);
    if (lane == 0) atomicAdd(&energy[batch[n]], p);
}

// -------------------- small prep kernels --------------------

__global__ __launch_bounds__(128) void a1_kernel(const float* __restrict__ Wout1,
                                                 const float* __restrict__ wread1,
                                                 const float* __restrict__ Wskip1,
                                                 const float* __restrict__ ae,
                                                 float* __restrict__ a1,
                                                 float* __restrict__ askip) {
    int f = threadIdx.x;
    float s = 0.f;
    for (int k = 0; k < FF; k++) s += Wout1[f * FF + k] * wread1[k];
    a1[f] = s;
    if (f < 10) {
        float t = 0.f;
        for (int k = 0; k < FF; k++) t += Wskip1[f * FF + k] * wread1[k];
        askip[f] = t + ae[f];
    }
}

__global__ __launch_bounds__(256) void transpose_kernel(const float* __restrict__ Wout0,
                                                        float* __restrict__ WoT) {
    int idx = blockIdx.x * 256 + threadIdx.x;
    int f = idx & 127;
    int k = idx >> 7;
    WoT[k * FF + f] = Wout0[f * FF + k];
}

__global__ __launch_bounds__(256) void gh_init_kernel(const float* __restrict__ wread0,
                                                      float* __restrict__ gh) {
    int idx = blockIdx.x * 256 + threadIdx.x;
    gh[idx] = wread0[idx & 127];
}

// -------------------- launch --------------------

extern "C" void kernel_launch(void* const* d_in, const int* in_sizes, int n_in,
                              void* d_out, int out_size, void* d_ws, size_t ws_size,
                              hipStream_t stream) {
    const float* pos    = (const float*)d_in[0];
    const float* attrs  = (const float*)d_in[1];
    const float* shifts = (const float*)d_in[2];
    const int*   ei     = (const int*)d_in[3];
    const int*   batch  = (const int*)d_in[4];
    const float* W_emb  = (const float*)d_in[6];
    const float* ae     = (const float*)d_in[7];
    const float* W_r    = (const float*)d_in[8];   // (2,8,F)
    const float* w_sh   = (const float*)d_in[9];   // (2,16)
    const float* W_out  = (const float*)d_in[10];  // (2,F,F)
    const float* W_skip = (const float*)d_in[11];  // (2,10,F)
    const float* w_read = (const float*)d_in[12];  // (2,F)

    float* energy = (float*)d_out;
    float* forces = energy + GG;

    float* ws  = (float*)d_ws;
    float* h0  = ws;                     // N*F
    float* h1  = h0 + (size_t)NN * FF;   // N*F
    float* agg = h1 + (size_t)NN * FF;   // N*F (reused as b0)
    float* gh  = agg + (size_t)NN * FF;  // N*F
    float* geo = gh + (size_t)NN * FF;   // 22*EE
    float* a1  = geo + (size_t)22 * EE;  // F
    float* askip = a1 + FF;              // 10
    float* WoT = askip + 16;             // F*F

    const int FEAT_BLOCKS = 2048;        // grid-stride, 4 waves/block
    const int geomBlocks = (EE + 255) / 256;
    const int gemmBlocks = (NN + 31) / 32;

    hipMemsetAsync(d_out, 0, (size_t)out_size * sizeof(float), stream);
    hipMemsetAsync(agg, 0, (size_t)NN * FF * sizeof(float), stream);

    h0_kernel<<<NN / 2, 256, 0, stream>>>(attrs, W_emb, h0);
    edge_geom<<<geomBlocks, 256, 0, stream>>>(pos, shifts, ei, w_sh, geo);
    a1_kernel<<<1, 128, 0, stream>>>(W_out + FF * FF, w_read + FF, W_skip + 10 * FF, ae,
                                     a1, askip);
    transpose_kernel<<<FF * FF / 256, 256, 0, stream>>>(W_out, WoT);

    // layer 0 forward
    edge_fwd_feat<<<FEAT_BLOCKS, 256, 0, stream>>>(geo, geo + G_S0, ei, h0, W_r, agg);
    // h1 = agg@Wout0 + attrs@Wskip0 ; energy += h1 . wread0
    node_gemm<true><<<gemmBlocks, 256, 0, stream>>>(agg, W_out, attrs, W_skip, w_read,
                                                    batch, h1, energy);

    // layer 1 forward
    hipMemsetAsync(agg, 0, (size_t)NN * FF * sizeof(float), stream);
    edge_fwd_feat<<<FEAT_BLOCKS, 256, 0, stream>>>(geo, geo + G_S1, ei, h1,
                                                   W_r + NBES * FF, agg);
    // layer-1 energy via dot with a1 (+ skip/e0 terms)
    e1_dot<<<(NN + 3) / 4, 256, 0, stream>>>(agg, attrs, a1, askip, batch, energy);

    // backward
    gh_init_kernel<<<NN * FF / 256, 256, 0, stream>>>(w_read, gh);
    edge_bwd_feat<true><<<FEAT_BLOCKS, 256, 0, stream>>>(geo, geo + G_S1, ei, h1,
                                                         W_r + NBES * FF, a1, nullptr, gh,
                                                         geo + G_DSP1, geo + G_DRP1);
    // b0 = gh @ Wout0^T (into agg buffer)
    node_gemm<false><<<gemmBlocks, 256, 0, stream>>>(gh, WoT, nullptr, nullptr, nullptr,
                                                     nullptr, agg, nullptr);
    // layer 0 backward
    edge_bwd_feat<false><<<FEAT_BLOCKS, 256, 0, stream>>>(geo, geo + G_S0, ei, h0,
                                                          W_r, nullptr, agg, nullptr,
                                                          geo + G_DSP0, geo + G_DRP0);
    // forces for both layers
    force_kernel<<<geomBlocks, 256, 0, stream>>>(pos, shifts, ei, w_sh, geo, forces);
}

// Round 4
// 2456.558 us; speedup vs baseline: 1.3258x; 1.3258x over previous
//
#include <hip/hip_runtime.h>

#define NN 50000
#define EE 800000
#define GG 64
#define FF 128
#define NBES 8
#define RMAXF 5.0f
#define PI_F 3.14159265358979323846f

// spherical harmonic constants
#define S3  1.7320508075688772f
#define S5  2.23606797749979f
#define S15 3.872983346207417f
#define C1c 2.091650066335189f   // sqrt(35/8)
#define C2c 10.246950765959598f  // sqrt(105)
#define C3c 1.62018517460196f    // sqrt(21/8)
#define C4c 1.3228756555322954f  // sqrt(7)/2
#define C5c 5.123475382979799f   // sqrt(105)/2
#define CCB 0.6324555320336759f  // sqrt(2/5)

__device__ __forceinline__ float shc_s(float x, float y, float z, const float* __restrict__ w) {
    float x2 = x * x, y2 = y * y, z2 = z * z;
    return w[0]
        + w[1] * (S3 * x) + w[2] * (S3 * y) + w[3] * (S3 * z)
        + w[4] * (S15 * x * y) + w[5] * (S15 * y * z) + w[6] * (0.5f * S5 * (3.f * z2 - 1.f))
        + w[7] * (S15 * x * z) + w[8] * (0.5f * S15 * (x2 - y2))
        + w[9] * (C1c * y * (3.f * x2 - y2)) + w[10] * (C2c * x * y * z)
        + w[11] * (C3c * y * (5.f * z2 - 1.f)) + w[12] * (C4c * z * (5.f * z2 - 3.f))
        + w[13] * (C3c * x * (5.f * z2 - 1.f)) + w[14] * (C5c * z * (x2 - y2))
        + w[15] * (C1c * x * (x2 - 3.f * y2));
}

__device__ __forceinline__ void shc_grad(float x, float y, float z, const float* __restrict__ w,
                                         float& gx, float& gy, float& gz) {
    float x2 = x * x, y2 = y * y, z2 = z * z;
    gx = w[1] * S3 + w[4] * (S15 * y) + w[7] * (S15 * z) + w[8] * (S15 * x)
       + w[9] * (6.f * C1c * x * y) + w[10] * (C2c * y * z) + w[13] * (C3c * (5.f * z2 - 1.f))
       + w[14] * (2.f * C5c * x * z) + w[15] * (3.f * C1c * (x2 - y2));
    gy = w[2] * S3 + w[4] * (S15 * x) + w[5] * (S15 * z) - w[8] * (S15 * y)
       + w[9] * (3.f * C1c * (x2 - y2)) + w[10] * (C2c * x * z) + w[11] * (C3c * (5.f * z2 - 1.f))
       - w[14] * (2.f * C5c * y * z) - w[15] * (6.f * C1c * x * y);
    gz = w[3] * S3 + w[5] * (S15 * y) + w[6] * (3.f * S5 * z) + w[7] * (S15 * x)
       + w[10] * (C2c * x * y) + w[11] * (10.f * C3c * y * z) + w[12] * (C4c * (15.f * z2 - 3.f))
       + w[13] * (10.f * C3c * x * z) + w[14] * (C5c * (x2 - y2));
}

// geo SoA layout (arrays of EE floats)
#define G_EB(k)  ((size_t)(k) * EE)
#define G_S0     ((size_t)8 * EE)
#define G_S1     ((size_t)9 * EE)
#define G_DB(k)  ((size_t)(10 + (k)) * EE)
#define G_DSP0   ((size_t)18 * EE)
#define G_DRP0   ((size_t)19 * EE)
#define G_DSP1   ((size_t)20 * EE)
#define G_DRP1   ((size_t)21 * EE)

// -------------------- geometry (thread-per-edge) --------------------

__global__ __launch_bounds__(256) void edge_geom(const float* __restrict__ pos,
                                                 const float* __restrict__ shifts,
                                                 const int* __restrict__ ei,
                                                 const float* __restrict__ wsh,  // (2,16)
                                                 float* __restrict__ geo) {
    int e = blockIdx.x * 256 + threadIdx.x;
    if (e >= EE) return;
    int snd = ei[e];
    int rcv = ei[EE + e];
    float vx = pos[rcv * 3 + 0] - pos[snd * 3 + 0] + shifts[e * 3 + 0];
    float vy = pos[rcv * 3 + 1] - pos[snd * 3 + 1] + shifts[e * 3 + 1];
    float vz = pos[rcv * 3 + 2] - pos[snd * 3 + 2] + shifts[e * 3 + 2];
    float r2 = vx * vx + vy * vy + vz * vz + 1e-12f;
    float r = sqrtf(r2);
    float inv_r = 1.0f / r;
    float x = vx * inv_r, y = vy * inv_r, z = vz * inv_r;
    float valid = (r < RMAXF) ? 1.f : 0.f;

    geo[G_S0 + e] = shc_s(x, y, z, wsh);
    geo[G_S1 + e] = shc_s(x, y, z, wsh + 16);

    float u = r * (1.0f / RMAXF);
    float th = PI_F * u;
    float s1 = sinf(th), c1 = cosf(th);
    float u2 = u * u, u3 = u2 * u, u5 = u2 * u3, u6 = u3 * u3, u7 = u6 * u, u8 = u6 * u2;
    float env = (1.f - 28.f * u6 + 48.f * u7 - 21.f * u8) * valid;
    float denv = (-168.f * u5 + 336.f * u6 - 168.f * u7) * (1.0f / RMAXF) * valid;
    float sk = s1, skm = 0.f, ck = c1, ckm = 1.f;
    float tc = 2.f * c1;
#pragma unroll
    for (int k = 1; k <= NBES; k++) {
        float b = CCB * sk * inv_r;
        geo[G_EB(k - 1) + e] = b * env;
        geo[G_DB(k - 1) + e] = CCB * (((float)k * PI_F * (1.0f / RMAXF)) * ck * inv_r
                                      - sk * inv_r * inv_r) * env
                               + b * denv;
        float sn = tc * sk - skm; skm = sk; sk = sn;
        float cn = tc * ck - ckm; ckm = ck; ck = cn;
    }
}

// -------------------- node prep --------------------

// h0 = attrs @ W_emb, 2 nodes per block
__global__ __launch_bounds__(256) void h0_kernel(const float* __restrict__ attrs,
                                                 const float* __restrict__ W_emb,
                                                 float* __restrict__ h0) {
    int sub = threadIdx.x >> 7;
    int f = threadIdx.x & 127;
    int n = blockIdx.x * 2 + sub;
    float acc = 0.f;
#pragma unroll
    for (int a = 0; a < 10; a++) acc += attrs[n * 10 + a] * W_emb[a * FF + f];
    h0[n * FF + f] = acc;
}

// -------------------- edge feature kernels (wave-per-edge, grid-stride) --------------------

__global__ __launch_bounds__(256) void edge_fwd_feat(const float* __restrict__ geo,
                                                     const float* __restrict__ geo_s,
                                                     const int* __restrict__ ei,
                                                     const float* __restrict__ h_src,
                                                     const float* __restrict__ Wr,
                                                     float* __restrict__ agg) {
    int wave = (blockIdx.x * 256 + threadIdx.x) >> 6;
    int lane = threadIdx.x & 63;
    int nwaves = gridDim.x * 4;
    int f0 = lane, f1 = lane + 64;
    float wr0[NBES], wr1[NBES];
#pragma unroll
    for (int k = 0; k < NBES; k++) { wr0[k] = Wr[k * FF + f0]; wr1[k] = Wr[k * FF + f1]; }

    for (int e = wave; e < EE; e += nwaves) {
        int snd = ei[e];
        int rcv = ei[EE + e];
        float s = geo_s[e];
        float R0 = 0.f, R1 = 0.f;
#pragma unroll
        for (int k = 0; k < NBES; k++) {
            float eb = geo[G_EB(k) + e];
            R0 += eb * wr0[k];
            R1 += eb * wr1[k];
        }
        float h0 = h_src[snd * FF + f0];
        float h1 = h_src[snd * FF + f1];
        atomicAdd(&agg[rcv * FF + f0], h0 * R0 * s);
        atomicAdd(&agg[rcv * FF + f1], h1 * R1 * s);
    }
}

template <bool LAYER1>
__global__ __launch_bounds__(256) void edge_bwd_feat(const float* __restrict__ geo,
                                                     const float* __restrict__ geo_s,
                                                     const int* __restrict__ ei,
                                                     const float* __restrict__ h_src,
                                                     const float* __restrict__ Wr,
                                                     const float* __restrict__ a1,
                                                     const float* __restrict__ b0,
                                                     float* __restrict__ gh,
                                                     float* __restrict__ dsp_out,
                                                     float* __restrict__ drp_out) {
    int wave = (blockIdx.x * 256 + threadIdx.x) >> 6;
    int lane = threadIdx.x & 63;
    int nwaves = gridDim.x * 4;
    int f0 = lane, f1 = lane + 64;
    float wr0[NBES], wr1[NBES];
#pragma unroll
    for (int k = 0; k < NBES; k++) { wr0[k] = Wr[k * FF + f0]; wr1[k] = Wr[k * FF + f1]; }
    float dm0u = 0.f, dm1u = 0.f;
    if (LAYER1) { dm0u = a1[f0]; dm1u = a1[f1]; }

    for (int e = wave; e < EE; e += nwaves) {
        int snd = ei[e];
        int rcv = ei[EE + e];
        float R0 = 0.f, R1 = 0.f, Rd0 = 0.f, Rd1 = 0.f;
#pragma unroll
        for (int k = 0; k < NBES; k++) {
            float eb = geo[G_EB(k) + e];
            float db = geo[G_DB(k) + e];
            R0 += eb * wr0[k];
            R1 += eb * wr1[k];
            Rd0 += db * wr0[k];
            Rd1 += db * wr1[k];
        }
        float dm0, dm1;
        if (LAYER1) { dm0 = dm0u; dm1 = dm1u; }
        else        { dm0 = b0[rcv * FF + f0]; dm1 = b0[rcv * FF + f1]; }
        float dh0 = dm0 * h_src[snd * FF + f0];
        float dh1 = dm1 * h_src[snd * FF + f1];
        float dsp = dh0 * R0 + dh1 * R1;
        float drp = dh0 * Rd0 + dh1 * Rd1;
#pragma unroll
        for (int o = 32; o > 0; o >>= 1) {
            dsp += __shfl_xor(dsp, o);
            drp += __shfl_xor(drp, o);
        }
        if (LAYER1) {
            float s = geo_s[e];
            atomicAdd(&gh[snd * FF + f0], dm0 * R0 * s);
            atomicAdd(&gh[snd * FF + f1], dm1 * R1 * s);
        }
        if (lane == 0) { dsp_out[e] = dsp; drp_out[e] = drp; }
    }
}

// -------------------- force finalize (thread-per-edge, both layers) --------------------

__global__ __launch_bounds__(256) void force_kernel(const float* __restrict__ pos,
                                                    const float* __restrict__ shifts,
                                                    const int* __restrict__ ei,
                                                    const float* __restrict__ wsh,
                                                    const float* __restrict__ geo,
                                                    float* __restrict__ forces) {
    int e = blockIdx.x * 256 + threadIdx.x;
    if (e >= EE) return;
    int snd = ei[e];
    int rcv = ei[EE + e];
    float vx = pos[rcv * 3 + 0] - pos[snd * 3 + 0] + shifts[e * 3 + 0];
    float vy = pos[rcv * 3 + 1] - pos[snd * 3 + 1] + shifts[e * 3 + 1];
    float vz = pos[rcv * 3 + 2] - pos[snd * 3 + 2] + shifts[e * 3 + 2];
    float r2 = vx * vx + vy * vy + vz * vz + 1e-12f;
    float r = sqrtf(r2);
    float inv_r = 1.0f / r;
    float x = vx * inv_r, y = vy * inv_r, z = vz * inv_r;

    float dsp0 = geo[G_DSP0 + e], drp0 = geo[G_DRP0 + e];
    float dsp1 = geo[G_DSP1 + e], drp1 = geo[G_DRP1 + e];
    float s0 = geo[G_S0 + e], s1v = geo[G_S1 + e];

    float g0x, g0y, g0z, g1x, g1y, g1z;
    shc_grad(x, y, z, wsh, g0x, g0y, g0z);
    shc_grad(x, y, z, wsh + 16, g1x, g1y, g1z);
    float gux = dsp0 * g0x + dsp1 * g1x;
    float guy = dsp0 * g0y + dsp1 * g1y;
    float guz = dsp0 * g0z + dsp1 * g1z;
    float gr = s0 * drp0 + s1v * drp1;
    float dgu = gux * x + guy * y + guz * z;
    float gvx = gr * x + inv_r * (gux - dgu * x);
    float gvy = gr * y + inv_r * (guy - dgu * y);
    float gvz = gr * z + inv_r * (guz - dgu * z);
    atomicAdd(&forces[snd * 3 + 0], gvx);
    atomicAdd(&forces[snd * 3 + 1], gvy);
    atomicAdd(&forces[snd * 3 + 2], gvz);
    atomicAdd(&forces[rcv * 3 + 0], -gvx);
    atomicAdd(&forces[rcv * 3 + 1], -gvy);
    atomicAdd(&forces[rcv * 3 + 2], -gvz);
}

// -------------------- node GEMM v2: C[n][f] = sum_k A[n][k] B[k][f] (+ epi) ------------
// B (128x128, 64KB) staged once per block in LDS; grid-stride over 32-node tiles.
// Thread (g = t>>5, fq = t&31): nodes nbase+g*4..+3, features f0=fq*4..+3, acc[4][4].
#define GEMM_BLOCKS 512
template <bool WITH_EPI>
__global__ __launch_bounds__(256, 4) void node_gemm(const float* __restrict__ A,
                                                    const float* __restrict__ B,
                                                    const float* __restrict__ attrs,
                                                    const float* __restrict__ Wskip,
                                                    const float* __restrict__ wread,
                                                    const int* __restrict__ batch,
                                                    float* __restrict__ C,
                                                    float* __restrict__ energy) {
    __shared__ float sb[FF][FF];
    int t = threadIdx.x;
    // stage B: 16384 floats = 4096 float4, 256 threads x 16
#pragma unroll
    for (int j = 0; j < 16; j++) {
        int flat4 = j * 256 + t;
        int row = flat4 >> 5;
        int col = (flat4 & 31) * 4;
        *(float4*)&sb[row][col] = *(const float4*)&B[row * FF + col];
    }
    __syncthreads();

    int g = t >> 5;                 // node sub-group 0..7
    int f0 = (t & 31) * 4;
    const int NTILES = (NN + 31) / 32;

    for (int tile = blockIdx.x; tile < NTILES; tile += GEMM_BLOCKS) {
        int nbase = tile * 32 + g * 4;
        float acc[4][4];
#pragma unroll
        for (int i = 0; i < 4; i++)
#pragma unroll
            for (int j = 0; j < 4; j++) acc[i][j] = 0.f;

#pragma unroll 2
        for (int kk = 0; kk < FF; kk += 4) {
            float4 bv0 = *(const float4*)&sb[kk + 0][f0];
            float4 bv1 = *(const float4*)&sb[kk + 1][f0];
            float4 bv2 = *(const float4*)&sb[kk + 2][f0];
            float4 bv3 = *(const float4*)&sb[kk + 3][f0];
#pragma unroll
            for (int ni = 0; ni < 4; ni++) {
                int n = nbase + ni;
                int nc = n < NN ? n : NN - 1;   // clamp; stores are guarded
                float4 av = *(const float4*)&A[(size_t)nc * FF + kk];
                acc[ni][0] += av.x * bv0.x + av.y * bv1.x + av.z * bv2.x + av.w * bv3.x;
                acc[ni][1] += av.x * bv0.y + av.y * bv1.y + av.z * bv2.y + av.w * bv3.y;
                acc[ni][2] += av.x * bv0.z + av.y * bv1.z + av.z * bv2.z + av.w * bv3.z;
                acc[ni][3] += av.x * bv0.w + av.y * bv1.w + av.z * bv2.w + av.w * bv3.w;
            }
        }

#pragma unroll
        for (int ni = 0; ni < 4; ni++) {
            int n = nbase + ni;
            bool valid = (n < NN);
            if (WITH_EPI) {
#pragma unroll
                for (int a = 0; a < 10; a++) {
                    float att = valid ? attrs[n * 10 + a] : 0.f;
                    float4 wk = *(const float4*)&Wskip[a * FF + f0];
                    acc[ni][0] += att * wk.x;
                    acc[ni][1] += att * wk.y;
                    acc[ni][2] += att * wk.z;
                    acc[ni][3] += att * wk.w;
                }
            }
            if (valid) {
                float4 out;
                out.x = acc[ni][0]; out.y = acc[ni][1];
                out.z = acc[ni][2]; out.w = acc[ni][3];
                *(float4*)&C[(size_t)n * FF + f0] = out;
            }
            if (WITH_EPI) {
                float4 wv = *(const float4*)&wread[f0];
                float p = acc[ni][0] * wv.x + acc[ni][1] * wv.y
                        + acc[ni][2] * wv.z + acc[ni][3] * wv.w;
                // reduce across the 32 f-lanes of this node group (stays within 32-lane span)
#pragma unroll
                for (int o = 16; o > 0; o >>= 1) p += __shfl_xor(p, o);
                if (valid && (t & 31) == 0) atomicAdd(&energy[batch[n]], p);
            }
        }
    }
}

// -------------------- layer-1 energy (dot) + e0, 4 nodes/block (1/wave) ----------------
__global__ __launch_bounds__(256) void e1_dot(const float* __restrict__ agg,
                                              const float* __restrict__ attrs,
                                              const float* __restrict__ a1,
                                              const float* __restrict__ askip,  // askip1+ae (10)
                                              const int* __restrict__ batch,
                                              float* __restrict__ energy) {
    int w = threadIdx.x >> 6;
    int lane = threadIdx.x & 63;
    int n = blockIdx.x * 4 + w;
    if (n >= NN) return;
    float p = agg[(size_t)n * FF + lane] * a1[lane]
            + agg[(size_t)n * FF + lane + 64] * a1[lane + 64];
    if (lane < 10) p += attrs[n * 10 + lane] * askip[lane];
#pragma unroll
    for (int o = 32; o > 0; o >>= 1) p += __shfl_xor(p, o);
    if (lane == 0) atomicAdd(&energy[batch[n]], p);
}

// -------------------- small prep kernels --------------------

__global__ __launch_bounds__(128) void a1_kernel(const float* __restrict__ Wout1,
                                                 const float* __restrict__ wread1,
                                                 const float* __restrict__ Wskip1,
                                                 const float* __restrict__ ae,
                                                 float* __restrict__ a1,
                                                 float* __restrict__ askip) {
    int f = threadIdx.x;
    float s = 0.f;
    for (int k = 0; k < FF; k++) s += Wout1[f * FF + k] * wread1[k];
    a1[f] = s;
    if (f < 10) {
        float t = 0.f;
        for (int k = 0; k < FF; k++) t += Wskip1[f * FF + k] * wread1[k];
        askip[f] = t + ae[f];
    }
}

__global__ __launch_bounds__(256) void transpose_kernel(const float* __restrict__ Wout0,
                                                        float* __restrict__ WoT) {
    int idx = blockIdx.x * 256 + threadIdx.x;
    int f = idx & 127;
    int k = idx >> 7;
    WoT[k * FF + f] = Wout0[f * FF + k];
}

__global__ __launch_bounds__(256) void gh_init_kernel(const float* __restrict__ wread0,
                                                      float* __restrict__ gh) {
    int idx = blockIdx.x * 256 + threadIdx.x;
    gh[idx] = wread0[idx & 127];
}

// -------------------- launch --------------------

extern "C" void kernel_launch(void* const* d_in, const int* in_sizes, int n_in,
                              void* d_out, int out_size, void* d_ws, size_t ws_size,
                              hipStream_t stream) {
    const float* pos    = (const float*)d_in[0];
    const float* attrs  = (const float*)d_in[1];
    const float* shifts = (const float*)d_in[2];
    const int*   ei     = (const int*)d_in[3];
    const int*   batch  = (const int*)d_in[4];
    const float* W_emb  = (const float*)d_in[6];
    const float* ae     = (const float*)d_in[7];
    const float* W_r    = (const float*)d_in[8];   // (2,8,F)
    const float* w_sh   = (const float*)d_in[9];   // (2,16)
    const float* W_out  = (const float*)d_in[10];  // (2,F,F)
    const float* W_skip = (const float*)d_in[11];  // (2,10,F)
    const float* w_read = (const float*)d_in[12];  // (2,F)

    float* energy = (float*)d_out;
    float* forces = energy + GG;

    float* ws  = (float*)d_ws;
    float* h0  = ws;                     // N*F
    float* h1  = h0 + (size_t)NN * FF;   // N*F
    float* agg = h1 + (size_t)NN * FF;   // N*F (reused as b0)
    float* gh  = agg + (size_t)NN * FF;  // N*F
    float* geo = gh + (size_t)NN * FF;   // 22*EE
    float* a1  = geo + (size_t)22 * EE;  // F
    float* askip = a1 + FF;              // 10
    float* WoT = askip + 16;             // F*F

    const int FEAT_BLOCKS = 2048;        // grid-stride, 4 waves/block
    const int geomBlocks = (EE + 255) / 256;

    hipMemsetAsync(d_out, 0, (size_t)out_size * sizeof(float), stream);
    hipMemsetAsync(agg, 0, (size_t)NN * FF * sizeof(float), stream);

    h0_kernel<<<NN / 2, 256, 0, stream>>>(attrs, W_emb, h0);
    edge_geom<<<geomBlocks, 256, 0, stream>>>(pos, shifts, ei, w_sh, geo);
    a1_kernel<<<1, 128, 0, stream>>>(W_out + FF * FF, w_read + FF, W_skip + 10 * FF, ae,
                                     a1, askip);
    transpose_kernel<<<FF * FF / 256, 256, 0, stream>>>(W_out, WoT);

    // layer 0 forward
    edge_fwd_feat<<<FEAT_BLOCKS, 256, 0, stream>>>(geo, geo + G_S0, ei, h0, W_r, agg);
    // h1 = agg@Wout0 + attrs@Wskip0 ; energy += h1 . wread0
    node_gemm<true><<<GEMM_BLOCKS, 256, 0, stream>>>(agg, W_out, attrs, W_skip, w_read,
                                                     batch, h1, energy);

    // layer 1 forward
    hipMemsetAsync(agg, 0, (size_t)NN * FF * sizeof(float), stream);
    edge_fwd_feat<<<FEAT_BLOCKS, 256, 0, stream>>>(geo, geo + G_S1, ei, h1,
                                                   W_r + NBES * FF, agg);
    // layer-1 energy via dot with a1 (+ skip/e0 terms)
    e1_dot<<<(NN + 3) / 4, 256, 0, stream>>>(agg, attrs, a1, askip, batch, energy);

    // backward
    gh_init_kernel<<<NN * FF / 256, 256, 0, stream>>>(w_read, gh);
    edge_bwd_feat<true><<<FEAT_BLOCKS, 256, 0, stream>>>(geo, geo + G_S1, ei, h1,
                                                         W_r + NBES * FF, a1, nullptr, gh,
                                                         geo + G_DSP1, geo + G_DRP1);
    // b0 = gh @ Wout0^T (into agg buffer)
    node_gemm<false><<<GEMM_BLOCKS, 256, 0, stream>>>(gh, WoT, nullptr, nullptr, nullptr,
                                                      nullptr, agg, nullptr);
    // layer 0 backward
    edge_bwd_feat<false><<<FEAT_BLOCKS, 256, 0, stream>>>(geo, geo + G_S0, ei, h0,
                                                          W_r, nullptr, agg, nullptr,
                                                          geo + G_DSP0, geo + G_DRP0);
    // forces for both layers
    force_kernel<<<geomBlocks, 256, 0, stream>>>(pos, shifts, ei, w_sh, geo, forces);
}

// Round 5
// 1755.358 us; speedup vs baseline: 1.8554x; 1.3995x over previous
//
#include <hip/hip_runtime.h>

#define NN 50000
#define EE 800000
#define GG 64
#define FF 128
#define NBES 8
#define RMAXF 5.0f
#define PI_F 3.14159265358979323846f

// spherical harmonic constants
#define S3  1.7320508075688772f
#define S5  2.23606797749979f
#define S15 3.872983346207417f
#define C1c 2.091650066335189f   // sqrt(35/8)
#define C2c 10.246950765959598f  // sqrt(105)
#define C3c 1.62018517460196f    // sqrt(21/8)
#define C4c 1.3228756555322954f  // sqrt(7)/2
#define C5c 5.123475382979799f   // sqrt(105)/2
#define CCB 0.6324555320336759f  // sqrt(2/5)

__device__ __forceinline__ float shc_s(float x, float y, float z, const float* __restrict__ w) {
    float x2 = x * x, y2 = y * y, z2 = z * z;
    return w[0]
        + w[1] * (S3 * x) + w[2] * (S3 * y) + w[3] * (S3 * z)
        + w[4] * (S15 * x * y) + w[5] * (S15 * y * z) + w[6] * (0.5f * S5 * (3.f * z2 - 1.f))
        + w[7] * (S15 * x * z) + w[8] * (0.5f * S15 * (x2 - y2))
        + w[9] * (C1c * y * (3.f * x2 - y2)) + w[10] * (C2c * x * y * z)
        + w[11] * (C3c * y * (5.f * z2 - 1.f)) + w[12] * (C4c * z * (5.f * z2 - 3.f))
        + w[13] * (C3c * x * (5.f * z2 - 1.f)) + w[14] * (C5c * z * (x2 - y2))
        + w[15] * (C1c * x * (x2 - 3.f * y2));
}

__device__ __forceinline__ void shc_grad(float x, float y, float z, const float* __restrict__ w,
                                         float& gx, float& gy, float& gz) {
    float x2 = x * x, y2 = y * y, z2 = z * z;
    gx = w[1] * S3 + w[4] * (S15 * y) + w[7] * (S15 * z) + w[8] * (S15 * x)
       + w[9] * (6.f * C1c * x * y) + w[10] * (C2c * y * z) + w[13] * (C3c * (5.f * z2 - 1.f))
       + w[14] * (2.f * C5c * x * z) + w[15] * (3.f * C1c * (x2 - y2));
    gy = w[2] * S3 + w[4] * (S15 * x) + w[5] * (S15 * z) - w[8] * (S15 * y)
       + w[9] * (3.f * C1c * (x2 - y2)) + w[10] * (C2c * x * z) + w[11] * (C3c * (5.f * z2 - 1.f))
       - w[14] * (2.f * C5c * y * z) - w[15] * (6.f * C1c * x * y);
    gz = w[3] * S3 + w[5] * (S15 * y) + w[6] * (3.f * S5 * z) + w[7] * (S15 * x)
       + w[10] * (C2c * x * y) + w[11] * (10.f * C3c * y * z) + w[12] * (C4c * (15.f * z2 - 3.f))
       + w[13] * (10.f * C3c * x * z) + w[14] * (C5c * (x2 - y2));
}

// geo SoA layout (arrays of EE floats)
#define G_EB(k)  ((size_t)(k) * EE)
#define G_S0     ((size_t)8 * EE)
#define G_S1     ((size_t)9 * EE)
#define G_DB(k)  ((size_t)(10 + (k)) * EE)
#define G_DSP0   ((size_t)18 * EE)
#define G_DRP0   ((size_t)19 * EE)
#define G_DSP1   ((size_t)20 * EE)
#define G_DRP1   ((size_t)21 * EE)

// -------------------- geometry (thread-per-edge) --------------------

__global__ __launch_bounds__(256) void edge_geom(const float* __restrict__ pos,
                                                 const float* __restrict__ shifts,
                                                 const int* __restrict__ ei,
                                                 const float* __restrict__ wsh,  // (2,16)
                                                 float* __restrict__ geo) {
    int e = blockIdx.x * 256 + threadIdx.x;
    if (e >= EE) return;
    int snd = ei[e];
    int rcv = ei[EE + e];
    float vx = pos[rcv * 3 + 0] - pos[snd * 3 + 0] + shifts[e * 3 + 0];
    float vy = pos[rcv * 3 + 1] - pos[snd * 3 + 1] + shifts[e * 3 + 1];
    float vz = pos[rcv * 3 + 2] - pos[snd * 3 + 2] + shifts[e * 3 + 2];
    float r2 = vx * vx + vy * vy + vz * vz + 1e-12f;
    float r = sqrtf(r2);
    float inv_r = 1.0f / r;
    float x = vx * inv_r, y = vy * inv_r, z = vz * inv_r;
    float valid = (r < RMAXF) ? 1.f : 0.f;

    geo[G_S0 + e] = shc_s(x, y, z, wsh);
    geo[G_S1 + e] = shc_s(x, y, z, wsh + 16);

    float u = r * (1.0f / RMAXF);
    float th = PI_F * u;
    float s1 = sinf(th), c1 = cosf(th);
    float u2 = u * u, u3 = u2 * u, u5 = u2 * u3, u6 = u3 * u3, u7 = u6 * u, u8 = u6 * u2;
    float env = (1.f - 28.f * u6 + 48.f * u7 - 21.f * u8) * valid;
    float denv = (-168.f * u5 + 336.f * u6 - 168.f * u7) * (1.0f / RMAXF) * valid;
    float sk = s1, skm = 0.f, ck = c1, ckm = 1.f;
    float tc = 2.f * c1;
#pragma unroll
    for (int k = 1; k <= NBES; k++) {
        float b = CCB * sk * inv_r;
        geo[G_EB(k - 1) + e] = b * env;
        geo[G_DB(k - 1) + e] = CCB * (((float)k * PI_F * (1.0f / RMAXF)) * ck * inv_r
                                      - sk * inv_r * inv_r) * env
                               + b * denv;
        float sn = tc * sk - skm; skm = sk; sk = sn;
        float cn = tc * ck - ckm; ckm = ck; ck = cn;
    }
}

// -------------------- node prep --------------------

// h0 = attrs @ W_emb, 2 nodes per block
__global__ __launch_bounds__(256) void h0_kernel(const float* __restrict__ attrs,
                                                 const float* __restrict__ W_emb,
                                                 float* __restrict__ h0) {
    int sub = threadIdx.x >> 7;
    int f = threadIdx.x & 127;
    int n = blockIdx.x * 2 + sub;
    float acc = 0.f;
#pragma unroll
    for (int a = 0; a < 10; a++) acc += attrs[n * 10 + a] * W_emb[a * FF + f];
    h0[n * FF + f] = acc;
}

// -------------------- edge feature kernels (wave-per-edge, grid-stride) --------------------

__global__ __launch_bounds__(256) void edge_fwd_feat(const float* __restrict__ geo,
                                                     const float* __restrict__ geo_s,
                                                     const int* __restrict__ ei,
                                                     const float* __restrict__ h_src,
                                                     const float* __restrict__ Wr,
                                                     float* __restrict__ agg) {
    int wave = (blockIdx.x * 256 + threadIdx.x) >> 6;
    int lane = threadIdx.x & 63;
    int nwaves = gridDim.x * 4;
    int f0 = lane, f1 = lane + 64;
    float wr0[NBES], wr1[NBES];
#pragma unroll
    for (int k = 0; k < NBES; k++) { wr0[k] = Wr[k * FF + f0]; wr1[k] = Wr[k * FF + f1]; }

    for (int e = wave; e < EE; e += nwaves) {
        int snd = ei[e];
        int rcv = ei[EE + e];
        float s = geo_s[e];
        float R0 = 0.f, R1 = 0.f;
#pragma unroll
        for (int k = 0; k < NBES; k++) {
            float eb = geo[G_EB(k) + e];
            R0 += eb * wr0[k];
            R1 += eb * wr1[k];
        }
        float h0 = h_src[snd * FF + f0];
        float h1 = h_src[snd * FF + f1];
        atomicAdd(&agg[rcv * FF + f0], h0 * R0 * s);
        atomicAdd(&agg[rcv * FF + f1], h1 * R1 * s);
    }
}

template <bool LAYER1>
__global__ __launch_bounds__(256) void edge_bwd_feat(const float* __restrict__ geo,
                                                     const float* __restrict__ geo_s,
                                                     const int* __restrict__ ei,
                                                     const float* __restrict__ h_src,
                                                     const float* __restrict__ Wr,
                                                     const float* __restrict__ a1,
                                                     const float* __restrict__ b0,
                                                     float* __restrict__ gh,
                                                     float* __restrict__ dsp_out,
                                                     float* __restrict__ drp_out) {
    int wave = (blockIdx.x * 256 + threadIdx.x) >> 6;
    int lane = threadIdx.x & 63;
    int nwaves = gridDim.x * 4;
    int f0 = lane, f1 = lane + 64;
    float wr0[NBES], wr1[NBES];
#pragma unroll
    for (int k = 0; k < NBES; k++) { wr0[k] = Wr[k * FF + f0]; wr1[k] = Wr[k * FF + f1]; }
    float dm0u = 0.f, dm1u = 0.f;
    if (LAYER1) { dm0u = a1[f0]; dm1u = a1[f1]; }

    for (int e = wave; e < EE; e += nwaves) {
        int snd = ei[e];
        int rcv = ei[EE + e];
        float R0 = 0.f, R1 = 0.f, Rd0 = 0.f, Rd1 = 0.f;
#pragma unroll
        for (int k = 0; k < NBES; k++) {
            float eb = geo[G_EB(k) + e];
            float db = geo[G_DB(k) + e];
            R0 += eb * wr0[k];
            R1 += eb * wr1[k];
            Rd0 += db * wr0[k];
            Rd1 += db * wr1[k];
        }
        float dm0, dm1;
        if (LAYER1) { dm0 = dm0u; dm1 = dm1u; }
        else        { dm0 = b0[rcv * FF + f0]; dm1 = b0[rcv * FF + f1]; }
        float dh0 = dm0 * h_src[snd * FF + f0];
        float dh1 = dm1 * h_src[snd * FF + f1];
        float dsp = dh0 * R0 + dh1 * R1;
        float drp = dh0 * Rd0 + dh1 * Rd1;
#pragma unroll
        for (int o = 32; o > 0; o >>= 1) {
            dsp += __shfl_xor(dsp, o);
            drp += __shfl_xor(drp, o);
        }
        if (LAYER1) {
            float s = geo_s[e];
            atomicAdd(&gh[snd * FF + f0], dm0 * R0 * s);
            atomicAdd(&gh[snd * FF + f1], dm1 * R1 * s);
        }
        if (lane == 0) { dsp_out[e] = dsp; drp_out[e] = drp; }
    }
}

// -------------------- force finalize (thread-per-edge, both layers) --------------------

__global__ __launch_bounds__(256) void force_kernel(const float* __restrict__ pos,
                                                    const float* __restrict__ shifts,
                                                    const int* __restrict__ ei,
                                                    const float* __restrict__ wsh,
                                                    const float* __restrict__ geo,
                                                    float* __restrict__ forces) {
    int e = blockIdx.x * 256 + threadIdx.x;
    if (e >= EE) return;
    int snd = ei[e];
    int rcv = ei[EE + e];
    float vx = pos[rcv * 3 + 0] - pos[snd * 3 + 0] + shifts[e * 3 + 0];
    float vy = pos[rcv * 3 + 1] - pos[snd * 3 + 1] + shifts[e * 3 + 1];
    float vz = pos[rcv * 3 + 2] - pos[snd * 3 + 2] + shifts[e * 3 + 2];
    float r2 = vx * vx + vy * vy + vz * vz + 1e-12f;
    float r = sqrtf(r2);
    float inv_r = 1.0f / r;
    float x = vx * inv_r, y = vy * inv_r, z = vz * inv_r;

    float dsp0 = geo[G_DSP0 + e], drp0 = geo[G_DRP0 + e];
    float dsp1 = geo[G_DSP1 + e], drp1 = geo[G_DRP1 + e];
    float s0 = geo[G_S0 + e], s1v = geo[G_S1 + e];

    float g0x, g0y, g0z, g1x, g1y, g1z;
    shc_grad(x, y, z, wsh, g0x, g0y, g0z);
    shc_grad(x, y, z, wsh + 16, g1x, g1y, g1z);
    float gux = dsp0 * g0x + dsp1 * g1x;
    float guy = dsp0 * g0y + dsp1 * g1y;
    float guz = dsp0 * g0z + dsp1 * g1z;
    float gr = s0 * drp0 + s1v * drp1;
    float dgu = gux * x + guy * y + guz * z;
    float gvx = gr * x + inv_r * (gux - dgu * x);
    float gvy = gr * y + inv_r * (guy - dgu * y);
    float gvz = gr * z + inv_r * (guz - dgu * z);
    atomicAdd(&forces[snd * 3 + 0], gvx);
    atomicAdd(&forces[snd * 3 + 1], gvy);
    atomicAdd(&forces[snd * 3 + 2], gvz);
    atomicAdd(&forces[rcv * 3 + 0], -gvx);
    atomicAdd(&forces[rcv * 3 + 1], -gvy);
    atomicAdd(&forces[rcv * 3 + 2], -gvz);
}

// -------------------- node GEMM v3: all-LDS inner loop --------------------
// B (128x128, 64KB) + A tile (32x128, 16KB) in LDS. Grid-stride over 32-node tiles.
// Thread (g = t>>5, fq = t&31): nodes tile*32+g*4..+3, features f0=fq*4..+3, acc[4][4].
// WITH_EPI: adds attrs@Wskip, writes per-node energy to node_e (no global energy atomics).
#define GEMM_BLOCKS 512
template <bool WITH_EPI>
__global__ __launch_bounds__(256, 2) void node_gemm(const float* __restrict__ A,
                                                    const float* __restrict__ B,
                                                    const float* __restrict__ attrs,
                                                    const float* __restrict__ Wskip,
                                                    const float* __restrict__ wread,
                                                    float* __restrict__ C,
                                                    float* __restrict__ node_e) {
    __shared__ float sb[FF][FF];   // 64 KB
    __shared__ float sa[32][FF];   // 16 KB
    int t = threadIdx.x;
    // stage B: 16384 floats = 4096 float4, 256 threads x 16
#pragma unroll
    for (int j = 0; j < 16; j++) {
        int flat4 = j * 256 + t;
        int row = flat4 >> 5;
        int col = (flat4 & 31) * 4;
        *(float4*)&sb[row][col] = *(const float4*)&B[row * FF + col];
    }

    int g = t >> 5;                 // node sub-group 0..7
    int f0 = (t & 31) * 4;
    const int NTILES = (NN + 31) / 32;

    for (int tile = blockIdx.x; tile < NTILES; tile += GEMM_BLOCKS) {
        __syncthreads();   // sa safe to overwrite; also orders first-iter B staging
        // stage A tile: 4096 floats = 1024 float4, 256 threads x 4
#pragma unroll
        for (int j = 0; j < 4; j++) {
            int flat4 = j * 256 + t;
            int row = flat4 >> 5;
            int col = (flat4 & 31) * 4;
            int n = tile * 32 + row;
            float4 v = make_float4(0.f, 0.f, 0.f, 0.f);
            if (n < NN) v = *(const float4*)&A[(size_t)n * FF + col];
            *(float4*)&sa[row][col] = v;
        }
        __syncthreads();

        float acc[4][4];
#pragma unroll
        for (int i = 0; i < 4; i++)
#pragma unroll
            for (int j = 0; j < 4; j++) acc[i][j] = 0.f;

        for (int kk = 0; kk < FF; kk += 4) {
            float4 bv0 = *(const float4*)&sb[kk + 0][f0];
            float4 bv1 = *(const float4*)&sb[kk + 1][f0];
            float4 bv2 = *(const float4*)&sb[kk + 2][f0];
            float4 bv3 = *(const float4*)&sb[kk + 3][f0];
#pragma unroll
            for (int ni = 0; ni < 4; ni++) {
                float4 av = *(const float4*)&sa[g * 4 + ni][kk];
                acc[ni][0] += av.x * bv0.x + av.y * bv1.x + av.z * bv2.x + av.w * bv3.x;
                acc[ni][1] += av.x * bv0.y + av.y * bv1.y + av.z * bv2.y + av.w * bv3.y;
                acc[ni][2] += av.x * bv0.z + av.y * bv1.z + av.z * bv2.z + av.w * bv3.z;
                acc[ni][3] += av.x * bv0.w + av.y * bv1.w + av.z * bv2.w + av.w * bv3.w;
            }
        }

#pragma unroll
        for (int ni = 0; ni < 4; ni++) {
            int n = tile * 32 + g * 4 + ni;
            bool valid = (n < NN);
            if (WITH_EPI) {
#pragma unroll
                for (int a = 0; a < 10; a++) {
                    float att = valid ? attrs[n * 10 + a] : 0.f;
                    float4 wk = *(const float4*)&Wskip[a * FF + f0];
                    acc[ni][0] += att * wk.x;
                    acc[ni][1] += att * wk.y;
                    acc[ni][2] += att * wk.z;
                    acc[ni][3] += att * wk.w;
                }
            }
            if (valid) {
                float4 out;
                out.x = acc[ni][0]; out.y = acc[ni][1];
                out.z = acc[ni][2]; out.w = acc[ni][3];
                *(float4*)&C[(size_t)n * FF + f0] = out;
            }
            if (WITH_EPI) {
                float4 wv = *(const float4*)&wread[f0];
                float p = acc[ni][0] * wv.x + acc[ni][1] * wv.y
                        + acc[ni][2] * wv.z + acc[ni][3] * wv.w;
#pragma unroll
                for (int o = 16; o > 0; o >>= 1) p += __shfl_xor(p, o);
                if (valid && (t & 31) == 0) node_e[n] = p;
            }
        }
    }
}

// -------------------- energy reduction (LDS-staged, few global atomics) ----------------
// energy[g] += sum_n [ node_e[n] + agg1[n].a1 + attrs[n].askip ]
#define ERED_BLOCKS 512
__global__ __launch_bounds__(256) void energy_kernel(const float* __restrict__ node_e,
                                                     const float* __restrict__ agg,
                                                     const float* __restrict__ attrs,
                                                     const float* __restrict__ a1,
                                                     const float* __restrict__ askip,
                                                     const int* __restrict__ batch,
                                                     float* __restrict__ energy) {
    __shared__ float eacc[GG];
    int t = threadIdx.x;
    if (t < GG) eacc[t] = 0.f;
    __syncthreads();

    int w = t >> 6;
    int lane = t & 63;
    for (int n = blockIdx.x * 4 + w; n < NN; n += ERED_BLOCKS * 4) {
        float p = agg[(size_t)n * FF + lane] * a1[lane]
                + agg[(size_t)n * FF + lane + 64] * a1[lane + 64];
        if (lane < 10) p += attrs[n * 10 + lane] * askip[lane];
        if (lane == 0) p += node_e[n];
#pragma unroll
        for (int o = 32; o > 0; o >>= 1) p += __shfl_xor(p, o);
        if (lane == 0) atomicAdd(&eacc[batch[n]], p);
    }
    __syncthreads();
    if (t < GG && eacc[t] != 0.f) atomicAdd(&energy[t], eacc[t]);
}

// -------------------- small prep kernels --------------------

__global__ __launch_bounds__(128) void a1_kernel(const float* __restrict__ Wout1,
                                                 const float* __restrict__ wread1,
                                                 const float* __restrict__ Wskip1,
                                                 const float* __restrict__ ae,
                                                 float* __restrict__ a1,
                                                 float* __restrict__ askip) {
    int f = threadIdx.x;
    float s = 0.f;
    for (int k = 0; k < FF; k++) s += Wout1[f * FF + k] * wread1[k];
    a1[f] = s;
    if (f < 10) {
        float t = 0.f;
        for (int k = 0; k < FF; k++) t += Wskip1[f * FF + k] * wread1[k];
        askip[f] = t + ae[f];
    }
}

__global__ __launch_bounds__(256) void transpose_kernel(const float* __restrict__ Wout0,
                                                        float* __restrict__ WoT) {
    int idx = blockIdx.x * 256 + threadIdx.x;
    int f = idx & 127;
    int k = idx >> 7;
    WoT[k * FF + f] = Wout0[f * FF + k];
}

__global__ __launch_bounds__(256) void gh_init_kernel(const float* __restrict__ wread0,
                                                      float* __restrict__ gh) {
    int idx = blockIdx.x * 256 + threadIdx.x;
    gh[idx] = wread0[idx & 127];
}

// -------------------- launch --------------------

extern "C" void kernel_launch(void* const* d_in, const int* in_sizes, int n_in,
                              void* d_out, int out_size, void* d_ws, size_t ws_size,
                              hipStream_t stream) {
    const float* pos    = (const float*)d_in[0];
    const float* attrs  = (const float*)d_in[1];
    const float* shifts = (const float*)d_in[2];
    const int*   ei     = (const int*)d_in[3];
    const int*   batch  = (const int*)d_in[4];
    const float* W_emb  = (const float*)d_in[6];
    const float* ae     = (const float*)d_in[7];
    const float* W_r    = (const float*)d_in[8];   // (2,8,F)
    const float* w_sh   = (const float*)d_in[9];   // (2,16)
    const float* W_out  = (const float*)d_in[10];  // (2,F,F)
    const float* W_skip = (const float*)d_in[11];  // (2,10,F)
    const float* w_read = (const float*)d_in[12];  // (2,F)

    float* energy = (float*)d_out;
    float* forces = energy + GG;

    float* ws  = (float*)d_ws;
    float* h0  = ws;                     // N*F
    float* h1  = h0 + (size_t)NN * FF;   // N*F
    float* agg = h1 + (size_t)NN * FF;   // N*F (reused as b0)
    float* gh  = agg + (size_t)NN * FF;  // N*F
    float* geo = gh + (size_t)NN * FF;   // 22*EE
    float* a1  = geo + (size_t)22 * EE;  // F
    float* askip = a1 + FF;              // 10 (padded 16)
    float* WoT = askip + 16;             // F*F
    float* node_e = WoT + FF * FF;       // N

    const int FEAT_BLOCKS = 2048;        // grid-stride, 4 waves/block
    const int geomBlocks = (EE + 255) / 256;

    hipMemsetAsync(d_out, 0, (size_t)out_size * sizeof(float), stream);
    hipMemsetAsync(agg, 0, (size_t)NN * FF * sizeof(float), stream);

    h0_kernel<<<NN / 2, 256, 0, stream>>>(attrs, W_emb, h0);
    edge_geom<<<geomBlocks, 256, 0, stream>>>(pos, shifts, ei, w_sh, geo);
    a1_kernel<<<1, 128, 0, stream>>>(W_out + FF * FF, w_read + FF, W_skip + 10 * FF, ae,
                                     a1, askip);
    transpose_kernel<<<FF * FF / 256, 256, 0, stream>>>(W_out, WoT);

    // layer 0 forward
    edge_fwd_feat<<<FEAT_BLOCKS, 256, 0, stream>>>(geo, geo + G_S0, ei, h0, W_r, agg);
    // h1 = agg@Wout0 + attrs@Wskip0 ; node_e = h1 . wread0 (per node)
    node_gemm<true><<<GEMM_BLOCKS, 256, 0, stream>>>(agg, W_out, attrs, W_skip, w_read,
                                                     h1, node_e);

    // layer 1 forward
    hipMemsetAsync(agg, 0, (size_t)NN * FF * sizeof(float), stream);
    edge_fwd_feat<<<FEAT_BLOCKS, 256, 0, stream>>>(geo, geo + G_S1, ei, h1,
                                                   W_r + NBES * FF, agg);
    // energy: e0 + layer0 (node_e) + layer1 (agg1.a1 + attrs.askip), LDS-staged reduction
    energy_kernel<<<ERED_BLOCKS, 256, 0, stream>>>(node_e, agg, attrs, a1, askip, batch,
                                                   energy);

    // backward
    gh_init_kernel<<<NN * FF / 256, 256, 0, stream>>>(w_read, gh);
    edge_bwd_feat<true><<<FEAT_BLOCKS, 256, 0, stream>>>(geo, geo + G_S1, ei, h1,
                                                         W_r + NBES * FF, a1, nullptr, gh,
                                                         geo + G_DSP1, geo + G_DRP1);
    // b0 = gh @ Wout0^T (into agg buffer)
    node_gemm<false><<<GEMM_BLOCKS, 256, 0, stream>>>(gh, WoT, nullptr, nullptr, nullptr,
                                                      agg, nullptr);
    // layer 0 backward
    edge_bwd_feat<false><<<FEAT_BLOCKS, 256, 0, stream>>>(geo, geo + G_S0, ei, h0,
                                                          W_r, nullptr, agg, nullptr,
                                                          geo + G_DSP0, geo + G_DRP0);
    // forces for both layers
    force_kernel<<<geomBlocks, 256, 0, stream>>>(pos, shifts, ei, w_sh, geo, forces);
}